// Round 1
// baseline (49.781 us; speedup 1.0000x reference)
//
#include <hip/hip_runtime.h>
#include <cmath>

// Problem constants (match the reference)
#define HH 256
#define WW 256
#define NG 1024
#define NB 2
static constexpr float FXc = 300.0f;
static constexpr float FYc = 300.0f;
static constexpr float CXc = 128.0f;
static constexpr float CYc = 128.0f;
static constexpr float EPSc = 1e-8f;
static constexpr float LOG2E = 1.4426950408889634f;

#if defined(__has_builtin)
#if __has_builtin(__builtin_amdgcn_exp2f)
#define FAST_EXP2(x) __builtin_amdgcn_exp2f(x)
#else
#define FAST_EXP2(x) exp2f(x)
#endif
#else
#define FAST_EXP2(x) exp2f(x)
#endif

__global__ __launch_bounds__(256) void render_kernel(
    const float* __restrict__ positions,   // [N,3]
    const float* __restrict__ colors,      // [N,3]
    const float* __restrict__ opacities,   // [N,1]
    const float* __restrict__ scales,      // [N,1]
    const float* __restrict__ qvec,        // [B,4]
    const float* __restrict__ tvec,        // [B,3]
    float* __restrict__ out)               // [B,3,H,W]
{
    // LDS: per gaussian two float4: (projx, projy, k, log2(op)), (r, g, b, 0)
    __shared__ float4 gs[2 * NG];  // 32 KB

    const int tid = blockIdx.x * 256 + threadIdx.x;
    const int b = tid >> 16;          // HW = 65536; b uniform per block
    const int p = tid & 65535;

    // --- per-block (redundant per-thread, wave-uniform) rotation setup ---
    float qw = qvec[b * 4 + 0], qx = qvec[b * 4 + 1];
    float qy = qvec[b * 4 + 2], qz = qvec[b * 4 + 3];
    float rin = rsqrtf(qw * qw + qx * qx + qy * qy + qz * qz);
    qw *= rin; qx *= rin; qy *= rin; qz *= rin;
    const float r00 = 1.0f - 2.0f * (qy * qy + qz * qz);
    const float r01 = 2.0f * (qx * qy - qz * qw);
    const float r02 = 2.0f * (qx * qz + qy * qw);
    const float r10 = 2.0f * (qx * qy + qz * qw);
    const float r11 = 1.0f - 2.0f * (qx * qx + qz * qz);
    const float r12 = 2.0f * (qy * qz - qx * qw);
    const float r20 = 2.0f * (qx * qz - qy * qw);
    const float r21 = 2.0f * (qy * qz + qx * qw);
    const float r22 = 1.0f - 2.0f * (qx * qx + qy * qy);
    const float t0 = tvec[b * 3 + 0], t1 = tvec[b * 3 + 1], t2 = tvec[b * 3 + 2];

    // --- stage all N gaussians into LDS (each thread projects 4) ---
    #pragma unroll
    for (int j = 0; j < NG / 256; ++j) {
        const int g = threadIdx.x + j * 256;
        const float X = positions[g * 3 + 0];
        const float Y = positions[g * 3 + 1];
        const float Z = positions[g * 3 + 2];
        const float cxp = r00 * X + r01 * Y + r02 * Z + t0;
        const float cyp = r10 * X + r11 * Y + r12 * Z + t1;
        const float czp = r20 * X + r21 * Y + r22 * Z + t2;
        const float iz = 1.0f / czp;
        const float ux = cxp * iz * FXc + CXc;
        const float uy = cyp * iz * FYc + CYc;
        const float s = scales[g];
        const float k = -0.5f * LOG2E / (s * s);
        const float lop = __log2f(opacities[g]);
        gs[2 * g + 0] = make_float4(ux, uy, k, lop);
        gs[2 * g + 1] = make_float4(colors[g * 3 + 0], colors[g * 3 + 1],
                                    colors[g * 3 + 2], 0.0f);
    }
    __syncthreads();

    // --- per-pixel accumulation over all gaussians ---
    const float px = (float)(p & (WW - 1));
    const float py = (float)(p >> 8);

    float den = 0.0f, ar = 0.0f, ag = 0.0f, ab = 0.0f;
    #pragma unroll 4
    for (int n = 0; n < NG; ++n) {
        const float4 g0 = gs[2 * n + 0];
        const float4 g1 = gs[2 * n + 1];
        const float dx = px - g0.x;
        const float dy = py - g0.y;
        const float d2 = fmaf(dy, dy, dx * dx);
        const float e = fmaf(g0.z, d2, g0.w);       // k*d2 + log2(op)
        const float w = FAST_EXP2(e);
        den += w;
        ar = fmaf(w, g1.x, ar);
        ag = fmaf(w, g1.y, ag);
        ab = fmaf(w, g1.z, ab);
    }

    const float inv = 1.0f / (den + EPSc);
    const size_t o = (size_t)b * 3 * 65536 + (size_t)p;
    out[o] = ar * inv;
    out[o + 65536] = ag * inv;
    out[o + 2 * 65536] = ab * inv;
}

extern "C" void kernel_launch(void* const* d_in, const int* in_sizes, int n_in,
                              void* d_out, int out_size, void* d_ws, size_t ws_size,
                              hipStream_t stream) {
    const float* positions = (const float*)d_in[0];
    const float* colors    = (const float*)d_in[1];
    const float* opacities = (const float*)d_in[2];
    const float* scales    = (const float*)d_in[3];
    const float* qvec      = (const float*)d_in[4];
    const float* tvec      = (const float*)d_in[5];
    // d_in[6] = pixel_coords, reconstructed analytically in-kernel
    float* out = (float*)d_out;

    const int n_pix_threads = NB * HH * WW;           // 131072
    render_kernel<<<dim3(n_pix_threads / 256), dim3(256), 0, stream>>>(
        positions, colors, opacities, scales, qvec, tvec, out);
}

// Round 2
// 37.595 us; speedup vs baseline: 1.3241x; 1.3241x over previous
//
#include <hip/hip_runtime.h>
#include <cmath>

// Problem constants (match the reference)
#define HH 256
#define WW 256
#define NG 1024
#define NB 2
static constexpr float FXc = 300.0f;
static constexpr float FYc = 300.0f;
static constexpr float CXc = 128.0f;
static constexpr float CYc = 128.0f;
static constexpr float EPSc = 1e-8f;
static constexpr float LOG2E = 1.4426950408889634f;

#if defined(__has_builtin)
#if __has_builtin(__builtin_amdgcn_exp2f)
#define FAST_EXP2(x) __builtin_amdgcn_exp2f(x)
#else
#define FAST_EXP2(x) exp2f(x)
#endif
#else
#define FAST_EXP2(x) exp2f(x)
#endif

// Layout:
//   grid = 1024 blocks (NB * 512), 256 threads.
//   Each block: one batch b, a 32x4-pixel tile (16 quads in x, 2 quads in y).
//   Thread = (quad_local [0,32), h [0,8)).  Each thread: 2x2 pixel quad,
//   gaussians g = i*8 + h (i in [0,128)) -> 8-way split, shfl_xor combine.
__global__ __launch_bounds__(256, 4) void render_kernel(
    const float* __restrict__ positions,   // [N,3]
    const float* __restrict__ colors,      // [N,3]
    const float* __restrict__ opacities,   // [N,1]
    const float* __restrict__ scales,      // [N,1]
    const float* __restrict__ qvec,        // [B,4]
    const float* __restrict__ tvec,        // [B,3]
    float* __restrict__ out)               // [B,3,H,W]
{
    __shared__ float4 gs[2 * NG];  // 32 KB: (ux,uy,k,log2op), (r,g,b,0)

    const int b = blockIdx.x >> 9;          // 512 blocks per batch
    const int tile = blockIdx.x & 511;
    const int x0 = (tile & 7) << 5;         // 8 tiles of 32 px in x
    const int y0 = (tile >> 3) << 2;        // 64 tiles of 4 px in y

    // --- per-thread (wave-uniform) rotation setup ---
    float qw = qvec[b * 4 + 0], qx = qvec[b * 4 + 1];
    float qy = qvec[b * 4 + 2], qz = qvec[b * 4 + 3];
    float rin = rsqrtf(qw * qw + qx * qx + qy * qy + qz * qz);
    qw *= rin; qx *= rin; qy *= rin; qz *= rin;
    const float r00 = 1.0f - 2.0f * (qy * qy + qz * qz);
    const float r01 = 2.0f * (qx * qy - qz * qw);
    const float r02 = 2.0f * (qx * qz + qy * qw);
    const float r10 = 2.0f * (qx * qy + qz * qw);
    const float r11 = 1.0f - 2.0f * (qx * qx + qz * qz);
    const float r12 = 2.0f * (qy * qz - qx * qw);
    const float r20 = 2.0f * (qx * qz - qy * qw);
    const float r21 = 2.0f * (qy * qz + qx * qw);
    const float r22 = 1.0f - 2.0f * (qx * qx + qy * qy);
    const float t0 = tvec[b * 3 + 0], t1 = tvec[b * 3 + 1], t2 = tvec[b * 3 + 2];

    // --- stage all N gaussians into LDS (each thread projects 4) ---
    #pragma unroll
    for (int j = 0; j < NG / 256; ++j) {
        const int g = threadIdx.x + j * 256;
        const float X = positions[g * 3 + 0];
        const float Y = positions[g * 3 + 1];
        const float Z = positions[g * 3 + 2];
        const float cxp = r00 * X + r01 * Y + r02 * Z + t0;
        const float cyp = r10 * X + r11 * Y + r12 * Z + t1;
        const float czp = r20 * X + r21 * Y + r22 * Z + t2;
        const float iz = 1.0f / czp;
        const float ux = cxp * iz * FXc + CXc;
        const float uy = cyp * iz * FYc + CYc;
        const float s = scales[g];
        const float k = -0.5f * LOG2E / (s * s);
        const float lop = __log2f(opacities[g]);
        gs[2 * g + 0] = make_float4(ux, uy, k, lop);
        gs[2 * g + 1] = make_float4(colors[g * 3 + 0], colors[g * 3 + 1],
                                    colors[g * 3 + 2], 0.0f);
    }
    __syncthreads();

    // --- quad / split decomposition ---
    const int quad = threadIdx.x >> 3;      // [0,32)
    const int h = threadIdx.x & 7;          // gaussian split
    const int px0i = x0 + ((quad & 15) << 1);
    const int py0i = y0 + ((quad >> 4) << 1);
    const float px = (float)px0i;
    const float py = (float)py0i;

    // accumulators: component x=(0,0), y=(+1,0), z=(0,+1), w=(+1,+1)
    float4 aden = make_float4(0.f, 0.f, 0.f, 0.f);
    float4 ar = aden, ag = aden, ab = aden;

    #pragma unroll 2
    for (int i = 0; i < NG / 8; ++i) {
        const int g = (i << 3) + h;
        const float4 g0 = gs[2 * g + 0];
        const float4 g1 = gs[2 * g + 1];
        const float k = g0.z;
        const float dx = px - g0.x;
        const float dy = py - g0.y;
        const float d2 = fmaf(dy, dy, dx * dx);
        const float e00 = fmaf(k, d2, g0.w);
        const float cx = k * fmaf(2.0f, dx, 1.0f);   // e(x+1)-e(x)
        const float cy = k * fmaf(2.0f, dy, 1.0f);   // e(y+1)-e(y)
        const float e10 = e00 + cx;
        const float e01 = e00 + cy;
        const float e11 = e10 + cy;
        const float w00 = FAST_EXP2(e00);
        const float w10 = FAST_EXP2(e10);
        const float w01 = FAST_EXP2(e01);
        const float w11 = FAST_EXP2(e11);
        aden.x += w00; aden.y += w10; aden.z += w01; aden.w += w11;
        ar.x = fmaf(w00, g1.x, ar.x); ar.y = fmaf(w10, g1.x, ar.y);
        ar.z = fmaf(w01, g1.x, ar.z); ar.w = fmaf(w11, g1.x, ar.w);
        ag.x = fmaf(w00, g1.y, ag.x); ag.y = fmaf(w10, g1.y, ag.y);
        ag.z = fmaf(w01, g1.y, ag.z); ag.w = fmaf(w11, g1.y, ag.w);
        ab.x = fmaf(w00, g1.z, ab.x); ab.y = fmaf(w10, g1.z, ab.y);
        ab.z = fmaf(w01, g1.z, ab.z); ab.w = fmaf(w11, g1.z, ab.w);
    }

    // --- butterfly combine across the 8-lane split group ---
    #pragma unroll
    for (int m = 1; m <= 4; m <<= 1) {
        aden.x += __shfl_xor(aden.x, m); aden.y += __shfl_xor(aden.y, m);
        aden.z += __shfl_xor(aden.z, m); aden.w += __shfl_xor(aden.w, m);
        ar.x += __shfl_xor(ar.x, m); ar.y += __shfl_xor(ar.y, m);
        ar.z += __shfl_xor(ar.z, m); ar.w += __shfl_xor(ar.w, m);
        ag.x += __shfl_xor(ag.x, m); ag.y += __shfl_xor(ag.y, m);
        ag.z += __shfl_xor(ag.z, m); ag.w += __shfl_xor(ag.w, m);
        ab.x += __shfl_xor(ab.x, m); ab.y += __shfl_xor(ab.y, m);
        ab.z += __shfl_xor(ab.z, m); ab.w += __shfl_xor(ab.w, m);
    }

    // --- epilogue: lanes h<4 each write one pixel of the quad ---
    if (h < 4) {
        float den, cr, cg, cb;
        if (h == 0)      { den = aden.x; cr = ar.x; cg = ag.x; cb = ab.x; }
        else if (h == 1) { den = aden.y; cr = ar.y; cg = ag.y; cb = ab.y; }
        else if (h == 2) { den = aden.z; cr = ar.z; cg = ag.z; cb = ab.z; }
        else             { den = aden.w; cr = ar.w; cg = ag.w; cb = ab.w; }
        const int pxx = px0i + (h & 1);
        const int pyy = py0i + (h >> 1);
        const float inv = 1.0f / (den + EPSc);
        const size_t o = (size_t)b * 3 * 65536 + (size_t)pyy * WW + pxx;
        out[o]           = cr * inv;
        out[o + 65536]   = cg * inv;
        out[o + 131072]  = cb * inv;
    }
}

extern "C" void kernel_launch(void* const* d_in, const int* in_sizes, int n_in,
                              void* d_out, int out_size, void* d_ws, size_t ws_size,
                              hipStream_t stream) {
    const float* positions = (const float*)d_in[0];
    const float* colors    = (const float*)d_in[1];
    const float* opacities = (const float*)d_in[2];
    const float* scales    = (const float*)d_in[3];
    const float* qvec      = (const float*)d_in[4];
    const float* tvec      = (const float*)d_in[5];
    float* out = (float*)d_out;

    render_kernel<<<dim3(NB * 512), dim3(256), 0, stream>>>(
        positions, colors, opacities, scales, qvec, tvec, out);
}